// Round 3
// baseline (260.014 us; speedup 1.0000x reference)
//
#include <hip/hip_runtime.h>
#include <float.h>
#include <stdint.h>

// Problem constants: B=64, H=W=32, C=256, D=H*W=1024, K=1024
#define B_   64
#define C_   256
#define D_   1024
#define K_   1024
#define M_   16384
#define NX_  16777216          // B*D*C = M*D
#define DISC_OFF NX_
#define LOSS_OFF (NX_ + M_)

typedef _Float16 h8 __attribute__((ext_vector_type(8)));
typedef float    f4 __attribute__((ext_vector_type(4)));

// Power-of-2 split scales (exact). acc = 2^20 * dot.
#define XSCALE 512.0f
#define ESCALE 2048.0f
#define DOT_UNSCALE_2 (2.0f / 1048576.0f)

// d_ws layout (float offsets).
#define WS_EH  0          // 1M fp16 = 524288 floats
#define WS_EL  524288
#define WS_CN  1048576    // 1024
#define WS_PCN 1049600    // 128*1024 = 131072
// pV aliases pcn (pcn is dead after colnorm2; stream order makes this safe)
#define WS_PV  1049600    // 16384*8 = 131072
#define WS_PI  1180672    // 16384*8 = 131072   (ends 1311744, same high-water)

__device__ __forceinline__ void async16(const _Float16* g, _Float16* l) {
    __builtin_amdgcn_global_load_lds(
        (const __attribute__((address_space(1))) unsigned int*)g,
        (__attribute__((address_space(3))) unsigned int*)l, 16, 0, 0);
}

// ---------------------------------------------------------------------------
// Fused split kernel. Blocks [0,512): E -> fragment-tiled fp16 hi/lo planes
// [nt][kt][lane][8] + colnorm partials. Blocks [512,8704): x -> same layout.
// ---------------------------------------------------------------------------
__global__ __launch_bounds__(256) void split_kernel(const float* __restrict__ x,
                                                    const float* __restrict__ E,
                                                    _Float16* __restrict__ Xh,
                                                    _Float16* __restrict__ Xl,
                                                    _Float16* __restrict__ Eh,
                                                    _Float16* __restrict__ El,
                                                    float* __restrict__ pcn) {
    const int bid = blockIdx.x;
    if (bid < 512) {
        // ---- E split + colnorm partials ----
        const int tid = bid * 256 + threadIdx.x;      // [0, 131072)
        const int n   = tid & 1023;
        const int o   = tid >> 10;                    // k-octet [0,128)
        const int d0  = o * 8;
        h8 hh, ll;
        float s = 0.f;
        #pragma unroll
        for (int i = 0; i < 8; ++i) {
            const float v = E[(size_t)(d0 + i) * K_ + n];
            s = fmaf(v, v, s);
            const float vs = v * ESCALE;
            const _Float16 h = (_Float16)vs;
            hh[i] = h;
            ll[i] = (_Float16)(vs - (float)h);
        }
        pcn[o * K_ + n] = s;
        const int nt   = n >> 4;
        const int kt   = o >> 2;
        const int lane = (n & 15) + (o & 3) * 16;
        const size_t off = ((size_t)(nt * 32 + kt) * 64 + lane) * 8;
        *(h8*)(Eh + off) = hh;
        *(h8*)(El + off) = ll;
    } else {
        // ---- x split ----
        const int tid = (bid - 512) * 256 + threadIdx.x;  // [0, 2097152)
        const int m   = tid & 16383;
        const int o   = tid >> 14;                        // [0,128)
        const int b   = m >> 8, c = m & 255;
        const int d0  = o * 8;
        const float* xp = x + ((size_t)(b * 1024 + d0) * 256) + c;
        h8 hh, ll;
        #pragma unroll
        for (int i = 0; i < 8; ++i) {
            const float v  = xp[(size_t)i * 256];
            const float vs = v * XSCALE;
            const _Float16 h = (_Float16)vs;
            hh[i] = h;
            ll[i] = (_Float16)(vs - (float)h);
        }
        const int mt   = m >> 4;
        const int kt   = o >> 2;
        const int lane = (m & 15) + (o & 3) * 16;
        const size_t off = ((size_t)(mt * 32 + kt) * 64 + lane) * 8;
        *(h8*)(Xh + off) = hh;
        *(h8*)(Xl + off) = ll;
    }
}

// colnorm: sum the 128 partials per column; zero the loss slot.
__global__ __launch_bounds__(256) void colnorm2_kernel(const float* __restrict__ pcn,
                                                       float* __restrict__ cn,
                                                       float* __restrict__ loss_slot) {
    __shared__ float sp[4][64];
    const int t    = threadIdx.x;
    const int col  = blockIdx.x * 64 + (t & 63);
    const int part = t >> 6;
    float s = 0.f;
    #pragma unroll 8
    for (int i = 0; i < 32; ++i) s += pcn[(part * 32 + i) * K_ + col];
    sp[part][t & 63] = s;
    __syncthreads();
    if (t < 64) cn[col] = (sp[0][t] + sp[1][t]) + (sp[2][t] + sp[3][t]);
    if (blockIdx.x == 0 && t == 0) *loss_slot = 0.0f;
}

// ---------------------------------------------------------------------------
// Split-fp16 MFMA distance GEMM + per-block argmin.
// Counted-vmcnt pipeline, sized for TWO desynchronized blocks per CU:
//   - tile 256x128, 4 waves (256 thr), wave out 128x64 (44 FLOP/LDS-byte).
//   - product folding: K' = 3072 (p = s/32), 96 steps; per step stage ONE
//     A-plane slice (16 KB) + ONE B-plane slice (8 KB) = 24 KB.
//   - THREE LDS buffers (72 KB) -> 2 blocks/CU (144 KB). Each SIMD carries 2
//     waves from DIFFERENT blocks whose barriers drift out of phase: one
//     block's ds_read burst overlaps the other's MFMA burst (m114), setprio
//     biases the MFMA wave (T5 role-split now exists across blocks).
//   - per step: vmcnt(6) [own stage(s) landed; stage(s+1) in flight] ->
//     s_barrier [all waves' stage(s) landed] -> issue stage(s+2) into
//     buf[(s+2)%3] (free: all waves finished reading it in step s-1) ->
//     12 ds_read -> 32 MFMA. vmcnt never drains to 0 until the last step.
// Grid 512 = 64 rt x 8 ct, bijective XCD swizzle, ct-major within each XCD.
// ---------------------------------------------------------------------------
__global__ __launch_bounds__(256, 2) void gemm_argmin_kernel(
        const _Float16* __restrict__ Xh, const _Float16* __restrict__ Xl,
        const _Float16* __restrict__ Eh, const _Float16* __restrict__ El,
        const float* __restrict__ cn,
        float* __restrict__ pV, int* __restrict__ pI) {
    extern __shared__ _Float16 smem[];   // 3 x 12288 fp16 = 72 KB
    const int t    = threadIdx.x;
    const int bid  = blockIdx.x;
    const int swz  = (bid & 7) * 64 + (bid >> 3);  // bijective, 512 % 8 == 0
    const int rt   = swz >> 3;            // 0..63
    const int ct   = swz & 7;             // 0..7
    const int wave = t >> 6, lane = t & 63;
    const int lo16 = lane & 15, hi4 = lane >> 4;
    const int wr   = wave & 1, wc = wave >> 1;     // 2M x 2N wave grid
    const int wr8  = wr * 8,  wc4 = wc * 4;
    const int mt0  = rt * 16, nt0 = ct * 8;
    const int n0g  = ct * 128;

    // Staging: 24 chunks/step (16 A + 8 B), 6 per wave, 1 KB each.
    // LDS layout per buffer: A chunks at id*512 (id 0..15), B at id*512
    // (id 16..23; B base 8192 == 16*512 so the formula is uniform).
    size_t gOff[6]; int lOff[6]; bool isA[6];
    #pragma unroll
    for (int i = 0; i < 6; ++i) {
        const int id = wave * 6 + i;
        lOff[i] = id * 512 + lane * 8;
        if (id < 16) {
            isA[i] = true;
            gOff[i] = (size_t)(mt0 + id) * 16384 + lane * 8;
        } else {
            isA[i] = false;
            gOff[i] = (size_t)(nt0 + (id - 16)) * 16384 + lane * 8;
        }
    }

    f4 acc[8][4];
    const f4 zero = {0.f, 0.f, 0.f, 0.f};
    #pragma unroll
    for (int m = 0; m < 8; ++m)
        #pragma unroll
        for (int n = 0; n < 4; ++n) acc[m][n] = zero;

    auto stage = [&](int s2) {
        const int p  = s2 >> 5;           // product: 0:(Ah,Bh) 1:(Ah,Bl) 2:(Al,Bh)
        const int kt = s2 & 31;
        const _Float16* Ap = (p < 2) ? Xh : Xl;
        const _Float16* Bp = (p == 1) ? El : Eh;
        _Float16* db = smem + (s2 % 3) * 12288;
        #pragma unroll
        for (int i = 0; i < 6; ++i)
            async16((isA[i] ? Ap : Bp) + gOff[i] + (size_t)kt * 512, db + lOff[i]);
    };

    auto body = [&](int s, bool doStage) {
        __builtin_amdgcn_s_barrier();          // all waves' step-s loads landed
        asm volatile("" ::: "memory");         // pin ds_reads below the barrier
        if (doStage) stage(s + 2);             // buf[(s+2)%3]==buf[(s-1)%3]: free
        const _Float16* rb = smem + (s % 3) * 12288;
        h8 Bf[4];
        #pragma unroll
        for (int n = 0; n < 4; ++n)
            Bf[n] = *(const h8*)(rb + 8192 + (wc4 + n) * 512 + lane * 8);
        __builtin_amdgcn_s_setprio(1);
        #pragma unroll
        for (int m = 0; m < 8; ++m) {
            const h8 Af = *(const h8*)(rb + (wr8 + m) * 512 + lane * 8);
            #pragma unroll
            for (int n = 0; n < 4; ++n)
                acc[m][n] = __builtin_amdgcn_mfma_f32_16x16x32_f16(Af, Bf[n], acc[m][n], 0, 0, 0);
        }
        __builtin_amdgcn_s_setprio(0);
    };

    // prologue: 2-deep prefetch (12 loads/thread in flight)
    stage(0); stage(1);

    for (int s = 0; s < 95; ++s) {
        asm volatile("s_waitcnt vmcnt(6)" ::: "memory");  // stage(s) landed
        body(s, s < 94);
    }
    asm volatile("s_waitcnt vmcnt(0)" ::: "memory");
    body(95, false);

    // ---- epilogue: per-row argmin over this block's 128 cols ----
    __syncthreads();
    float* cV = (float*)smem;          // [256][2]
    int*   cI = (int*)(cV + 512);      // [256][2]

    float cnv[4];
    #pragma unroll
    for (int n = 0; n < 4; ++n) cnv[n] = cn[n0g + wc * 64 + n * 16 + lo16];

    #pragma unroll
    for (int m = 0; m < 8; ++m) {
        #pragma unroll
        for (int r = 0; r < 4; ++r) {
            float bv = FLT_MAX;
            int   bi = 0;
            #pragma unroll
            for (int n = 0; n < 4; ++n) {   // ascending col => first-index tie-break
                const float v = cnv[n] - acc[m][n][r] * DOT_UNSCALE_2;
                if (v < bv) { bv = v; bi = wc * 64 + n * 16 + lo16; }
            }
            #pragma unroll
            for (int msk = 1; msk < 16; msk <<= 1) {
                const float ov = __shfl_xor(bv, msk, 64);
                const int   oi = __shfl_xor(bi, msk, 64);
                if (ov < bv || (ov == bv && oi < bi)) { bv = ov; bi = oi; }
            }
            if (lo16 == 0) {
                const int row = wr * 128 + m * 16 + hi4 * 4 + r;
                cV[row * 2 + wc] = bv;
                cI[row * 2 + wc] = bi;
            }
        }
    }
    __syncthreads();
    {
        float bv = FLT_MAX;
        int   bi = 0;
        #pragma unroll
        for (int g = 0; g < 2; ++g) {          // ascending n-base, strict <
            const float v = cV[t * 2 + g];
            const int   i = cI[t * 2 + g];
            if (v < bv || (v == bv && i < bi)) { bv = v; bi = i; }
        }
        const int row = rt * 256 + t;
        pV[row * 8 + ct] = bv;
        pI[row * 8 + ct] = n0g + bi;
    }
}

// ---------------------------------------------------------------------------
// Final argmin across the 8 col-tiles (ascending, numpy tie-break).
// ---------------------------------------------------------------------------
__global__ __launch_bounds__(256) void reduce_kernel(const float* __restrict__ pV,
                                                     const int* __restrict__ pI,
                                                     float* __restrict__ disc) {
    const int rid = blockIdx.x * 256 + threadIdx.x;
    float bv = FLT_MAX;
    int   bi = 0;
    #pragma unroll
    for (int c = 0; c < 8; ++c) {
        const float v = pV[rid * 8 + c];
        const int   i = pI[rid * 8 + c];
        if (v < bv || (v == bv && i < bi)) { bv = v; bi = i; }
    }
    disc[rid] = (float)bi;
}

// ---------------------------------------------------------------------------
// finalize: one block per d. E row d staged in LDS (4 KB), gather via ds_read.
// q = x + (e - x); loss += 1.25*mean((x-e)^2). Fully coalesced x/q streams.
// ---------------------------------------------------------------------------
__global__ __launch_bounds__(256) void finalize_kernel(const float* __restrict__ x,
                                                       const float* __restrict__ E,
                                                       const float* __restrict__ discf,
                                                       float* __restrict__ out,
                                                       float* __restrict__ loss) {
    __shared__ float Erow[1024];
    const int t = threadIdx.x;
    const int d = blockIdx.x;
    *(float4*)&Erow[t * 4] = *(const float4*)(E + (size_t)d * K_ + t * 4);
    __syncthreads();

    const int bl = t >> 6;           // wave id -> b offset
    const int c4 = (t & 63) * 4;
    float lsum = 0.f;
    #pragma unroll 4
    for (int bg = 0; bg < 64; bg += 4) {
        const int b = bg + bl;
        const float4 id4 = *(const float4*)(discf + b * 256 + c4);
        const size_t xoff = ((size_t)(b * 1024 + d) << 8) + c4;
        const float4 xv = *(const float4*)(x + xoff);
        const float e0 = Erow[(int)id4.x];
        const float e1 = Erow[(int)id4.y];
        const float e2 = Erow[(int)id4.z];
        const float e3 = Erow[(int)id4.w];
        float4 qv;
        qv.x = xv.x + (e0 - xv.x);
        qv.y = xv.y + (e1 - xv.y);
        qv.z = xv.z + (e2 - xv.z);
        qv.w = xv.w + (e3 - xv.w);
        *(float4*)(out + xoff) = qv;
        const float d0 = xv.x - e0, d1 = xv.y - e1, d2 = xv.z - e2, d3 = xv.w - e3;
        lsum += fmaf(d0, d0, fmaf(d1, d1, fmaf(d2, d2, d3 * d3)));
    }

    #pragma unroll
    for (int off = 32; off > 0; off >>= 1)
        lsum += __shfl_down(lsum, off);
    __shared__ float wsum[4];
    if ((t & 63) == 0) wsum[t >> 6] = lsum;
    __syncthreads();
    if (t == 0) {
        const float s = (wsum[0] + wsum[1]) + (wsum[2] + wsum[3]);
        atomicAdd(loss, s * (1.25f / 16777216.0f));
    }
}

// ---------------------------------------------------------------------------
extern "C" void kernel_launch(void* const* d_in, const int* in_sizes, int n_in,
                              void* d_out, int out_size, void* d_ws, size_t ws_size,
                              hipStream_t stream) {
    (void)in_sizes; (void)n_in; (void)out_size; (void)ws_size;
    const float* x = (const float*)d_in[0];   // (64,32,32,256) f32
    const float* E = (const float*)d_in[1];   // (1024,1024)    f32
    float* out = (float*)d_out;
    float* ws  = (float*)d_ws;

    _Float16* Eh = (_Float16*)(ws + WS_EH);
    _Float16* El = (_Float16*)(ws + WS_EL);
    float* cn    = ws + WS_CN;
    float* pcn   = ws + WS_PCN;
    float* pV    = ws + WS_PV;                // aliases pcn (dead after colnorm2)
    int*   pI    = (int*)(ws + WS_PI);

    _Float16* Xh = (_Float16*)out;            // q-region scratch (overwritten by finalize)
    _Float16* Xl = (_Float16*)out + NX_;
    float* disc  = out + DISC_OFF;
    float* loss  = out + LOSS_OFF;

    // Allow 72 KB dynamic LDS (default cap is 64 KB; gfx950 WG limit 160 KB).
    hipFuncSetAttribute((const void*)gemm_argmin_kernel,
                        hipFuncAttributeMaxDynamicSharedMemorySize, 73728);

    split_kernel   <<<8704, 256, 0, stream>>>(x, E, Xh, Xl, Eh, El, pcn);
    colnorm2_kernel<<<16,   256, 0, stream>>>(pcn, cn, loss);
    gemm_argmin_kernel<<<512, 256, 73728, stream>>>(Xh, Xl, Eh, El, cn, pV, pI);
    reduce_kernel  <<<64,   256, 0, stream>>>(pV, pI, disc);
    finalize_kernel<<<1024, 256, 0, stream>>>(x, E, disc, out, loss);
}

// Round 4
// 245.533 us; speedup vs baseline: 1.0590x; 1.0590x over previous
//
#include <hip/hip_runtime.h>
#include <float.h>
#include <stdint.h>

// Problem constants: B=64, H=W=32, C=256, D=H*W=1024, K=1024
#define B_   64
#define C_   256
#define D_   1024
#define K_   1024
#define M_   16384
#define NX_  16777216          // B*D*C = M*D
#define DISC_OFF NX_
#define LOSS_OFF (NX_ + M_)

typedef _Float16 h8 __attribute__((ext_vector_type(8)));
typedef float    f4 __attribute__((ext_vector_type(4)));

// Power-of-2 split scales (exact). acc = 2^20 * dot.
#define XSCALE 512.0f
#define ESCALE 2048.0f
#define DOT_UNSCALE_2 (2.0f / 1048576.0f)

// d_ws layout (float offsets).
#define WS_EH  0          // 1M fp16 = 524288 floats
#define WS_EL  524288
#define WS_CN  1048576    // 1024
#define WS_PCN 1049600    // 128*1024 = 131072
// pV aliases pcn (pcn is dead after colnorm2; stream order makes this safe)
#define WS_PV  1049600    // 16384*4 = 65536
#define WS_PI  1180672    // 16384*4 = 65536

__device__ __forceinline__ void async16(const _Float16* g, _Float16* l) {
    __builtin_amdgcn_global_load_lds(
        (const __attribute__((address_space(1))) unsigned int*)g,
        (__attribute__((address_space(3))) unsigned int*)l, 16, 0, 0);
}

// ---------------------------------------------------------------------------
// Fused split kernel. Blocks [0,512): E -> fragment-tiled fp16 hi/lo planes
// [nt][kt][lane][8] + colnorm partials. Blocks [512,8704): x -> same layout.
// ---------------------------------------------------------------------------
__global__ __launch_bounds__(256) void split_kernel(const float* __restrict__ x,
                                                    const float* __restrict__ E,
                                                    _Float16* __restrict__ Xh,
                                                    _Float16* __restrict__ Xl,
                                                    _Float16* __restrict__ Eh,
                                                    _Float16* __restrict__ El,
                                                    float* __restrict__ pcn) {
    const int bid = blockIdx.x;
    if (bid < 512) {
        // ---- E split + colnorm partials ----
        const int tid = bid * 256 + threadIdx.x;      // [0, 131072)
        const int n   = tid & 1023;
        const int o   = tid >> 10;                    // k-octet [0,128)
        const int d0  = o * 8;
        h8 hh, ll;
        float s = 0.f;
        #pragma unroll
        for (int i = 0; i < 8; ++i) {
            const float v = E[(size_t)(d0 + i) * K_ + n];
            s = fmaf(v, v, s);
            const float vs = v * ESCALE;
            const _Float16 h = (_Float16)vs;
            hh[i] = h;
            ll[i] = (_Float16)(vs - (float)h);
        }
        pcn[o * K_ + n] = s;
        const int nt   = n >> 4;
        const int kt   = o >> 2;
        const int lane = (n & 15) + (o & 3) * 16;
        const size_t off = ((size_t)(nt * 32 + kt) * 64 + lane) * 8;
        *(h8*)(Eh + off) = hh;
        *(h8*)(El + off) = ll;
    } else {
        // ---- x split ----
        const int tid = (bid - 512) * 256 + threadIdx.x;  // [0, 2097152)
        const int m   = tid & 16383;
        const int o   = tid >> 14;                        // [0,128)
        const int b   = m >> 8, c = m & 255;
        const int d0  = o * 8;
        const float* xp = x + ((size_t)(b * 1024 + d0) * 256) + c;
        h8 hh, ll;
        #pragma unroll
        for (int i = 0; i < 8; ++i) {
            const float v  = xp[(size_t)i * 256];
            const float vs = v * XSCALE;
            const _Float16 h = (_Float16)vs;
            hh[i] = h;
            ll[i] = (_Float16)(vs - (float)h);
        }
        const int mt   = m >> 4;
        const int kt   = o >> 2;
        const int lane = (m & 15) + (o & 3) * 16;
        const size_t off = ((size_t)(mt * 32 + kt) * 64 + lane) * 8;
        *(h8*)(Xh + off) = hh;
        *(h8*)(Xl + off) = ll;
    }
}

// colnorm: sum the 128 partials per column; zero the loss slot.
__global__ __launch_bounds__(256) void colnorm2_kernel(const float* __restrict__ pcn,
                                                       float* __restrict__ cn,
                                                       float* __restrict__ loss_slot) {
    __shared__ float sp[4][64];
    const int t    = threadIdx.x;
    const int col  = blockIdx.x * 64 + (t & 63);
    const int part = t >> 6;
    float s = 0.f;
    #pragma unroll 8
    for (int i = 0; i < 32; ++i) s += pcn[(part * 32 + i) * K_ + col];
    sp[part][t & 63] = s;
    __syncthreads();
    if (t < 64) cn[col] = (sp[0][t] + sp[1][t]) + (sp[2][t] + sp[3][t]);
    if (blockIdx.x == 0 && t == 0) *loss_slot = 0.0f;
}

// ---------------------------------------------------------------------------
// Split-fp16 MFMA distance GEMM + per-block argmin.
// m201-style phase-interleaved counted-vmcnt pipeline:
//   - BM=BN=256, BK=32, product folding -> 96 logical K-steps.
//   - 3 LDS buffers x 32 KB (96 KB); stage(s+2) issued during step s ->
//     HBM lead >= 2 steps (~2 x 1500 cyc >> 900 cyc latency).
//   - per step: vmcnt(4) [own stage(s) loads landed] -> s_barrier [ALL
//     waves' stage(s) landed AND all reads of buf[(s-1)%3] retired, since
//     each wave's lgkmcnt(0) precedes its last MFMA cluster] -> then TWO
//     phases of {4-5 ds_read_b128; 2 global_load_lds for s+2 (into
//     buf[(s-1)%3], safe post-barrier); lgkmcnt(0); setprio(1); 16 MFMA;
//     setprio(0)}. vmcnt never drains to 0 until the tail (T4).
//   - 8 waves (2M x 4N), wave out 128x64, acc[8][4]; Bf regs persist
//     across both phases.
// Grid 256 = 64 rt x 4 ct (1 block/CU), bijective XCD swizzle: each XCD
// gets 8 consecutive rt x 4 ct -> shared A panels in its L2.
// ---------------------------------------------------------------------------
__global__ __launch_bounds__(512, 2) void gemm_argmin_kernel(
        const _Float16* __restrict__ Xh, const _Float16* __restrict__ Xl,
        const _Float16* __restrict__ Eh, const _Float16* __restrict__ El,
        const float* __restrict__ cn,
        float* __restrict__ pV, int* __restrict__ pI) {
    extern __shared__ _Float16 smem[];   // 3 x 16384 fp16 = 96 KB
    const int t    = threadIdx.x;
    const int bid  = blockIdx.x;
    const int swz  = (bid & 7) * 32 + (bid >> 3);  // bijective, 256 % 8 == 0
    const int rt   = swz >> 2;            // 0..63
    const int ct   = swz & 3;             // 0..3
    const int wave = t >> 6, lane = t & 63;
    const int lo16 = lane & 15, hi4 = lane >> 4;
    const int wr   = wave & 1, wc = wave >> 1;     // 2M x 4N wave grid
    const int wr8  = wr * 8,  wc4 = wc * 4;
    const int mt0  = rt * 16, nt0 = ct * 16;
    const int n0g  = ct * 256;

    // Staging: 32 chunks/step (16 A + 16 B), 4 per wave, 1 KB each.
    // Buffer layout: A chunk mt at mt*512, B chunk nt at 8192 + nt*512.
    size_t gOff[4]; int lOff[4]; bool isA[4];
    #pragma unroll
    for (int i = 0; i < 4; ++i) {
        const int id = wave * 4 + i;
        if (id < 16) {
            isA[i] = true;
            gOff[i] = (size_t)(mt0 + id) * 16384 + lane * 8;
            lOff[i] = id * 512 + lane * 8;
        } else {
            isA[i] = false;
            gOff[i] = (size_t)(nt0 + (id - 16)) * 16384 + lane * 8;
            lOff[i] = 8192 + (id - 16) * 512 + lane * 8;
        }
    }

    f4 acc[8][4];
    const f4 zero = {0.f, 0.f, 0.f, 0.f};
    #pragma unroll
    for (int m = 0; m < 8; ++m)
        #pragma unroll
        for (int n = 0; n < 4; ++n) acc[m][n] = zero;

    auto stageHalf = [&](int s2, int half) {
        const int p  = s2 >> 5;           // product: 0:(Ah,Bh) 1:(Ah,Bl) 2:(Al,Bh)
        const int kt = s2 & 31;
        const _Float16* Ap = (p < 2) ? Xh : Xl;
        const _Float16* Bp = (p == 1) ? El : Eh;
        _Float16* db = smem + (s2 % 3) * 16384;
        #pragma unroll
        for (int jj = 0; jj < 2; ++jj) {
            const int i = half * 2 + jj;
            async16((isA[i] ? Ap : Bp) + gOff[i] + (size_t)kt * 512, db + lOff[i]);
        }
    };

    auto step = [&](int s, bool doStage, bool last) {
        if (last) { asm volatile("s_waitcnt vmcnt(0)" ::: "memory"); }
        else      { asm volatile("s_waitcnt vmcnt(4)" ::: "memory"); }
        __builtin_amdgcn_s_barrier();
        const _Float16* rb = smem + (s % 3) * 16384;
        // ---- phase 0: B frags + A-half 0 ----
        h8 Bf[4], Af[4];
        #pragma unroll
        for (int n = 0; n < 4; ++n)
            Bf[n] = *(const h8*)(rb + 8192 + (wc4 + n) * 512 + lane * 8);
        #pragma unroll
        for (int mm = 0; mm < 4; ++mm)
            Af[mm] = *(const h8*)(rb + (wr8 + mm) * 512 + lane * 8);
        if (doStage) stageHalf(s + 2, 0);
        asm volatile("s_waitcnt lgkmcnt(0)" ::: "memory");
        __builtin_amdgcn_s_setprio(1);
        #pragma unroll
        for (int mm = 0; mm < 4; ++mm)
            #pragma unroll
            for (int n = 0; n < 4; ++n)
                acc[mm][n] = __builtin_amdgcn_mfma_f32_16x16x32_f16(Af[mm], Bf[n], acc[mm][n], 0, 0, 0);
        __builtin_amdgcn_s_setprio(0);
        // ---- phase 1: A-half 1 (Bf persists) ----
        h8 Ag[4];
        #pragma unroll
        for (int mm = 0; mm < 4; ++mm)
            Ag[mm] = *(const h8*)(rb + (4 + wr8 + mm) * 512 + lane * 8);
        if (doStage) stageHalf(s + 2, 1);
        asm volatile("s_waitcnt lgkmcnt(0)" ::: "memory");
        __builtin_amdgcn_s_setprio(1);
        #pragma unroll
        for (int mm = 0; mm < 4; ++mm)
            #pragma unroll
            for (int n = 0; n < 4; ++n)
                acc[4 + mm][n] = __builtin_amdgcn_mfma_f32_16x16x32_f16(Ag[mm], Bf[n], acc[4 + mm][n], 0, 0, 0);
        __builtin_amdgcn_s_setprio(0);
    };

    // prologue: 2-step prefetch (8 loads/thread in flight)
    stageHalf(0, 0); stageHalf(0, 1);
    stageHalf(1, 0); stageHalf(1, 1);

    for (int s = 0; s < 94; ++s) step(s, true, false);
    step(94, false, false);
    step(95, false, true);

    // ---- epilogue: per-row argmin over this block's 256 cols ----
    __syncthreads();
    float* cV = (float*)smem;          // [256][4]
    int*   cI = (int*)(cV + 1024);     // [256][4]

    float cnv[4];
    #pragma unroll
    for (int n = 0; n < 4; ++n) cnv[n] = cn[n0g + wc * 64 + n * 16 + lo16];

    #pragma unroll
    for (int m = 0; m < 8; ++m) {
        #pragma unroll
        for (int r = 0; r < 4; ++r) {
            float bv = FLT_MAX;
            int   bi = 0;
            #pragma unroll
            for (int n = 0; n < 4; ++n) {   // ascending col => first-index tie-break
                const float v = cnv[n] - acc[m][n][r] * DOT_UNSCALE_2;
                if (v < bv) { bv = v; bi = wc * 64 + n * 16 + lo16; }
            }
            #pragma unroll
            for (int msk = 1; msk < 16; msk <<= 1) {
                const float ov = __shfl_xor(bv, msk, 64);
                const int   oi = __shfl_xor(bi, msk, 64);
                if (ov < bv || (ov == bv && oi < bi)) { bv = ov; bi = oi; }
            }
            if (lo16 == 0) {
                const int row = wr * 128 + m * 16 + hi4 * 4 + r;
                cV[row * 4 + wc] = bv;
                cI[row * 4 + wc] = bi;
            }
        }
    }
    __syncthreads();
    if (t < 256) {
        float bv = FLT_MAX;
        int   bi = 0;
        #pragma unroll
        for (int g = 0; g < 4; ++g) {          // ascending n-base, strict <
            const float v = cV[t * 4 + g];
            const int   i = cI[t * 4 + g];
            if (v < bv || (v == bv && i < bi)) { bv = v; bi = i; }
        }
        const int row = rt * 256 + t;
        pV[row * 4 + ct] = bv;
        pI[row * 4 + ct] = n0g + bi;
    }
}

// ---------------------------------------------------------------------------
// Final argmin across the 4 col-tiles (ascending, numpy tie-break).
// ---------------------------------------------------------------------------
__global__ __launch_bounds__(256) void reduce_kernel(const float* __restrict__ pV,
                                                     const int* __restrict__ pI,
                                                     float* __restrict__ disc) {
    const int rid = blockIdx.x * 256 + threadIdx.x;
    float bv = FLT_MAX;
    int   bi = 0;
    #pragma unroll
    for (int c = 0; c < 4; ++c) {
        const float v = pV[rid * 4 + c];
        const int   i = pI[rid * 4 + c];
        if (v < bv || (v == bv && i < bi)) { bv = v; bi = i; }
    }
    disc[rid] = (float)bi;
}

// ---------------------------------------------------------------------------
// finalize: one block per d. E row d staged in LDS (4 KB), gather via ds_read.
// q = x + (e - x); loss += 1.25*mean((x-e)^2). Fully coalesced x/q streams.
// ---------------------------------------------------------------------------
__global__ __launch_bounds__(256) void finalize_kernel(const float* __restrict__ x,
                                                       const float* __restrict__ E,
                                                       const float* __restrict__ discf,
                                                       float* __restrict__ out,
                                                       float* __restrict__ loss) {
    __shared__ float Erow[1024];
    const int t = threadIdx.x;
    const int d = blockIdx.x;
    *(float4*)&Erow[t * 4] = *(const float4*)(E + (size_t)d * K_ + t * 4);
    __syncthreads();

    const int bl = t >> 6;           // wave id -> b offset
    const int c4 = (t & 63) * 4;
    float lsum = 0.f;
    #pragma unroll 4
    for (int bg = 0; bg < 64; bg += 4) {
        const int b = bg + bl;
        const float4 id4 = *(const float4*)(discf + b * 256 + c4);
        const size_t xoff = ((size_t)(b * 1024 + d) << 8) + c4;
        const float4 xv = *(const float4*)(x + xoff);
        const float e0 = Erow[(int)id4.x];
        const float e1 = Erow[(int)id4.y];
        const float e2 = Erow[(int)id4.z];
        const float e3 = Erow[(int)id4.w];
        float4 qv;
        qv.x = xv.x + (e0 - xv.x);
        qv.y = xv.y + (e1 - xv.y);
        qv.z = xv.z + (e2 - xv.z);
        qv.w = xv.w + (e3 - xv.w);
        *(float4*)(out + xoff) = qv;
        const float d0 = xv.x - e0, d1 = xv.y - e1, d2 = xv.z - e2, d3 = xv.w - e3;
        lsum += fmaf(d0, d0, fmaf(d1, d1, fmaf(d2, d2, d3 * d3)));
    }

    #pragma unroll
    for (int off = 32; off > 0; off >>= 1)
        lsum += __shfl_down(lsum, off);
    __shared__ float wsum[4];
    if ((t & 63) == 0) wsum[t >> 6] = lsum;
    __syncthreads();
    if (t == 0) {
        const float s = (wsum[0] + wsum[1]) + (wsum[2] + wsum[3]);
        atomicAdd(loss, s * (1.25f / 16777216.0f));
    }
}

// ---------------------------------------------------------------------------
extern "C" void kernel_launch(void* const* d_in, const int* in_sizes, int n_in,
                              void* d_out, int out_size, void* d_ws, size_t ws_size,
                              hipStream_t stream) {
    (void)in_sizes; (void)n_in; (void)out_size; (void)ws_size;
    const float* x = (const float*)d_in[0];   // (64,32,32,256) f32
    const float* E = (const float*)d_in[1];   // (1024,1024)    f32
    float* out = (float*)d_out;
    float* ws  = (float*)d_ws;

    _Float16* Eh = (_Float16*)(ws + WS_EH);
    _Float16* El = (_Float16*)(ws + WS_EL);
    float* cn    = ws + WS_CN;
    float* pcn   = ws + WS_PCN;
    float* pV    = ws + WS_PV;                // aliases pcn (dead after colnorm2)
    int*   pI    = (int*)(ws + WS_PI);

    _Float16* Xh = (_Float16*)out;            // q-region scratch (overwritten by finalize)
    _Float16* Xl = (_Float16*)out + NX_;
    float* disc  = out + DISC_OFF;
    float* loss  = out + LOSS_OFF;

    // Allow 96 KB dynamic LDS (default cap is 64 KB; gfx950 WG limit 160 KB).
    hipFuncSetAttribute((const void*)gemm_argmin_kernel,
                        hipFuncAttributeMaxDynamicSharedMemorySize, 98304);

    split_kernel   <<<8704, 256, 0, stream>>>(x, E, Xh, Xl, Eh, El, pcn);
    colnorm2_kernel<<<16,   256, 0, stream>>>(pcn, cn, loss);
    gemm_argmin_kernel<<<256, 512, 98304, stream>>>(Xh, Xl, Eh, El, cn, pV, pI);
    reduce_kernel  <<<64,   256, 0, stream>>>(pV, pI, disc);
    finalize_kernel<<<1024, 256, 0, stream>>>(x, E, disc, out, loss);
}